// Round 2
// baseline (1211.194 us; speedup 1.0000x reference)
//
#include <hip/hip_runtime.h>

// Problem constants (B,S,D,H,HD) = (4,1024,1024,16,64)
constexpr int Bb = 4, Ss = 1024, Dd = 1024, Hh = 16;

// ---------------------------------------------------------------------------
// GEMM: C[M,N] = A[M,K] * W[K,N] + bias[N]   (fp32, LDS-tiled 64x64x16)
// block = 256 threads, each computes a 4x4 micro-tile.
// ---------------------------------------------------------------------------
__global__ __launch_bounds__(256) void gemm_bias_f32(
    const float* __restrict__ A, const float* __restrict__ W,
    const float* __restrict__ bias, float* __restrict__ C,
    int M, int N, int K) {
  constexpr int BM = 64, BN = 64, BK = 16;
  __shared__ float As[BK][BM + 2];  // +2 pad: conflict-free transposed store
  __shared__ float Bs[BK][BN];

  const int tid = threadIdx.x;
  const int tx = tid & 15;   // n-coord of micro-tile
  const int ty = tid >> 4;   // m-coord of micro-tile
  const int m0 = blockIdx.y * BM;
  const int n0 = blockIdx.x * BN;

  const int tk = tid & 15;   // A-load k
  const int tmb = tid >> 4;  // A-load m base
  const int wn = tid & 63;   // B-load n
  const int wkb = tid >> 6;  // B-load k base

  float acc[4][4] = {};

  for (int k0 = 0; k0 < K; k0 += BK) {
#pragma unroll
    for (int i = 0; i < 4; i++) {
      As[tk][tmb + 16 * i] = A[(size_t)(m0 + tmb + 16 * i) * K + (k0 + tk)];
    }
#pragma unroll
    for (int i = 0; i < 4; i++) {
      Bs[wkb + 4 * i][wn] = W[(size_t)(k0 + wkb + 4 * i) * N + (n0 + wn)];
    }
    __syncthreads();
#pragma unroll
    for (int k = 0; k < BK; k++) {
      float a[4];
#pragma unroll
      for (int i = 0; i < 4; i++) a[i] = As[k][ty * 4 + i];
      const float4 b4 = *(const float4*)&Bs[k][tx * 4];
      const float bb[4] = {b4.x, b4.y, b4.z, b4.w};
#pragma unroll
      for (int i = 0; i < 4; i++)
#pragma unroll
        for (int j = 0; j < 4; j++) acc[i][j] += a[i] * bb[j];
    }
    __syncthreads();
  }

#pragma unroll
  for (int i = 0; i < 4; i++) {
    const int m = m0 + ty * 4 + i;
    const int n = n0 + tx * 4;
    float4 o;
    o.x = acc[i][0] + bias[n + 0];
    o.y = acc[i][1] + bias[n + 1];
    o.z = acc[i][2] + bias[n + 2];
    o.w = acc[i][3] + bias[n + 3];
    *(float4*)&C[(size_t)m * N + n] = o;
  }
}

// ---------------------------------------------------------------------------
// Fused attention: scores (QK^T/8 + causal + mask) -> softmax -> write w
//                  -> PV -> write merged-head activations.
// Grid: (S/16, B*H). Block: 256 threads.
// Thread (qr = tid/16, tc = tid%16) owns q-row (q0+qr) and keys j = tc + 16*jj,
// jj = 0..63, kept in 64 registers. K/V staged per 128-key chunk in LDS.
// Causal: chunks entirely above the diagonal are skipped (p == 0 exactly,
// matching exp(-10000 - max) == 0 in fp32).
// ---------------------------------------------------------------------------
__global__ __launch_bounds__(256) void attn_fused(
    const float* __restrict__ qkv,   // [B*S][3*D]; cols 0:q 1024:k 2048:v
    const float* __restrict__ mask,  // [B][S]
    float* __restrict__ w_out,       // [B*H][S][S]
    float* __restrict__ a_out) {     // [B*S][D] merged heads
  constexpr int QT = 16, CK = 128, PAD = 68;  // PAD keeps float4 align + banks spread
  __shared__ float Qs[QT][PAD];
  __shared__ float KVs[CK][PAD];

  const int qt = blockIdx.x;
  const int bh = blockIdx.y;
  const int b = bh >> 4, h = bh & 15;
  const int q0 = qt * QT;
  const int tid = threadIdx.x;
  const int tc = tid & 15;
  const int qr = tid >> 4;
  const int qrl = (tid & 63) >> 4;  // q-row within this wave (0..3)
  const int qglob = q0 + qr;

  // stage Q tile: 16 rows x 64 cols, one float4 per thread
  {
    const int d4 = tid & 15, r = tid >> 4;
    const float4* src =
        (const float4*)(qkv + (size_t)(b * Ss + q0 + r) * (3 * Dd) + h * 64);
    *(float4*)&Qs[r][d4 * 4] = src[d4];
  }

  float s[64];
#pragma unroll
  for (int jj = 0; jj < 64; jj++) s[jj] = -10000.0f;

  // ---- scores ----
#pragma unroll
  for (int c = 0; c < 8; c++) {
    if (c * CK <= q0 + QT - 1) {  // block-uniform causal skip
      __syncthreads();
      {
        const int d4 = tid & 15, r = tid >> 4;
#pragma unroll
        for (int i = 0; i < 8; i++) {
          const int row = r + 16 * i;
          const float4* src = (const float4*)(qkv +
              (size_t)(b * Ss + c * CK + row) * (3 * Dd) + Dd + h * 64);
          *(float4*)&KVs[row][d4 * 4] = src[d4];
        }
      }
      __syncthreads();
#pragma unroll
      for (int jl = 0; jl < 8; jl++) {
        const int jloc = tc + 16 * jl;
        float ax = 0.f, ay = 0.f, az = 0.f, aw = 0.f;
#pragma unroll
        for (int d4 = 0; d4 < 16; d4++) {
          const float4 qv = *(const float4*)&Qs[qr][d4 * 4];
          const float4 kv = *(const float4*)&KVs[jloc][d4 * 4];
          ax += qv.x * kv.x;
          ay += qv.y * kv.y;
          az += qv.z * kv.z;
          aw += qv.w * kv.w;
        }
        const int jglobal = c * CK + jloc;
        if (jglobal <= qglob) s[c * 8 + jl] = (ax + ay + az + aw) * 0.125f;
      }
    }
  }

  // ---- add input mask, softmax across the 16 lanes of this q-row ----
  float mx = -3.0e38f;
#pragma unroll
  for (int jj = 0; jj < 64; jj++) {
    s[jj] += mask[b * Ss + (tc + 16 * jj)];
    mx = fmaxf(mx, s[jj]);
  }
#pragma unroll
  for (int mm = 1; mm < 16; mm <<= 1) mx = fmaxf(mx, __shfl_xor(mx, mm));
  float sum = 0.f;
#pragma unroll
  for (int jj = 0; jj < 64; jj++) {
    s[jj] = __expf(s[jj] - mx);
    sum += s[jj];
  }
#pragma unroll
  for (int mm = 1; mm < 16; mm <<= 1) sum += __shfl_xor(sum, mm);
  const float inv = 1.0f / sum;
#pragma unroll
  for (int jj = 0; jj < 64; jj++) s[jj] *= inv;

  // ---- write attention probs ----
  float* wrow = w_out + ((size_t)bh * Ss + qglob) * Ss;
#pragma unroll
  for (int jj = 0; jj < 64; jj++) wrow[tc + 16 * jj] = s[jj];

  // ---- PV: A[qr][d] = sum_j p[j] * V[j][d]; thread owns d = tc*4..tc*4+3 ----
  float av0 = 0.f, av1 = 0.f, av2 = 0.f, av3 = 0.f;
#pragma unroll
  for (int c = 0; c < 8; c++) {
    if (c * CK <= q0 + QT - 1) {
      __syncthreads();
      {
        const int d4 = tid & 15, r = tid >> 4;
#pragma unroll
        for (int i = 0; i < 8; i++) {
          const int row = r + 16 * i;
          const float4* src = (const float4*)(qkv +
              (size_t)(b * Ss + c * CK + row) * (3 * Dd) + 2 * Dd + h * 64);
          *(float4*)&KVs[row][d4 * 4] = src[d4];
        }
      }
      __syncthreads();
#pragma unroll
      for (int jl = 0; jl < CK; jl++) {
        // p for key (c*CK + jl) lives in reg s[c*8 + jl/16] of lane
        // (qrl*16 + jl%16) of this wave (same q-row).
        const float pj = __shfl(s[c * 8 + (jl >> 4)], (qrl << 4) + (jl & 15));
        const float4 vv = *(const float4*)&KVs[jl][tc * 4];
        av0 += pj * vv.x;
        av1 += pj * vv.y;
        av2 += pj * vv.z;
        av3 += pj * vv.w;
      }
    }
  }
  float4 o = {av0, av1, av2, av3};
  *(float4*)&a_out[(size_t)(b * Ss + qglob) * Dd + h * 64 + tc * 4] = o;
}

// ---------------------------------------------------------------------------
extern "C" void kernel_launch(void* const* d_in, const int* in_sizes, int n_in,
                              void* d_out, int out_size, void* d_ws,
                              size_t ws_size, hipStream_t stream) {
  const float* x = (const float*)d_in[0];
  const float* mask = (const float*)d_in[1];
  const float* w_attn = (const float*)d_in[2];
  const float* b_attn = (const float*)d_in[3];
  const float* w_proj = (const float*)d_in[4];
  const float* b_proj = (const float*)d_in[5];

  float* out_a = (float*)d_out;                 // [4,1024,1024]
  float* out_w = out_a + (size_t)Bb * Ss * Dd;  // [4,16,1024,1024]

  float* qkv = (float*)d_ws;                            // [4096][3072] = 48 MB
  float* amerged = qkv + (size_t)(Bb * Ss) * (3 * Dd);  // [4096][1024] = 16 MB

  // 1) QKV projection
  gemm_bias_f32<<<dim3((3 * Dd) / 64, (Bb * Ss) / 64), 256, 0, stream>>>(
      x, w_attn, b_attn, qkv, Bb * Ss, 3 * Dd, Dd);

  // 2) fused scores + softmax + w-write + PV
  attn_fused<<<dim3(Ss / 16, Bb * Hh), 256, 0, stream>>>(qkv, mask, out_w,
                                                         amerged);

  // 3) output projection
  gemm_bias_f32<<<dim3(Dd / 64, (Bb * Ss) / 64), 256, 0, stream>>>(
      amerged, w_proj, b_proj, out_a, Bb * Ss, Dd, Dd);
}

// Round 5
// 485.820 us; speedup vs baseline: 2.4931x; 2.4931x over previous
//
#include <hip/hip_runtime.h>
#include <hip/hip_bf16.h>

constexpr int Bb = 4, Ss = 1024, Dd = 1024, Hh = 16;

typedef __attribute__((ext_vector_type(8))) short short8;
typedef __attribute__((ext_vector_type(4))) float f32x4;

static __device__ __forceinline__ ushort f2bf(float f) {
  union { __hip_bfloat16 h; ushort u; } cv;
  cv.h = __float2bfloat16(f);
  return cv.u;
}

// ---------------------------------------------------------------------------
// elementwise fp32 -> bf16 cast, 4 elems/thread
// ---------------------------------------------------------------------------
__global__ __launch_bounds__(256) void cast_f32_bf16(
    const float* __restrict__ in, ushort* __restrict__ out) {
  const int i = (blockIdx.x * 256 + threadIdx.x) * 4;
  const float4 v = *(const float4*)&in[i];
  ushort4 o;
  o.x = f2bf(v.x); o.y = f2bf(v.y); o.z = f2bf(v.z); o.w = f2bf(v.w);
  *(ushort4*)&out[i] = o;
}

// ---------------------------------------------------------------------------
// fp32 [R][C] -> bf16 [C][R]  (32x32 LDS tile transpose)
// ---------------------------------------------------------------------------
__global__ __launch_bounds__(256) void transpose_cast(
    const float* __restrict__ in, ushort* __restrict__ out, int R, int C) {
  __shared__ float T[32][33];
  const int c0 = blockIdx.x * 32, r0 = blockIdx.y * 32;
  const int t = threadIdx.x;
  const int r = t >> 3, c4 = (t & 7) * 4;
  const float4 v = *(const float4*)&in[(size_t)(r0 + r) * C + c0 + c4];
  T[r][c4 + 0] = v.x; T[r][c4 + 1] = v.y;
  T[r][c4 + 2] = v.z; T[r][c4 + 3] = v.w;
  __syncthreads();
  const int cc = t >> 3, rr4 = (t & 7) * 4;
  ushort4 o;
  o.x = f2bf(T[rr4 + 0][cc]); o.y = f2bf(T[rr4 + 1][cc]);
  o.z = f2bf(T[rr4 + 2][cc]); o.w = f2bf(T[rr4 + 3][cc]);
  *(ushort4*)&out[(size_t)(c0 + cc) * R + r0 + rr4] = o;
}

// ---------------------------------------------------------------------------
// bf16 GEMM, both operands K-contiguous: C[M][N] = A[M][K] * Bt[N][K]^T + bias
// FIXED: stage 4x uint4 (=32 shorts) per row, not 2 (which left half the
// K-slice uninitialized -> NaN garbage into MFMA).
// ---------------------------------------------------------------------------
template <int BM, int BN, bool OUT_BF16>
__global__ __launch_bounds__(256) void gemm_bt(
    const ushort* __restrict__ A, const ushort* __restrict__ Bt,
    const float* __restrict__ bias, void* __restrict__ Cout,
    int M, int N, int K) {
  constexpr int LDK = 40;
  constexpr int TM = BM / 32, TN = BN / 32;
  __shared__ ushort As[BM * LDK];
  __shared__ ushort Bs[BN * LDK];
  const int tid = threadIdx.x;
  const int wv = tid >> 6, lane = tid & 63;
  const int l15 = lane & 15, quad = lane >> 4;
  const int m0 = blockIdx.y * BM, n0 = blockIdx.x * BN;
  const int wrow = (wv >> 1) * (BM / 2), wcol = (wv & 1) * (BN / 2);

  f32x4 acc[TM][TN] = {};

  for (int k0 = 0; k0 < K; k0 += 32) {
#pragma unroll
    for (int idx = tid; idx < BM * 4; idx += 256) {
      const int row = idx >> 2, kp = (idx & 3) * 8;
      *(uint4*)&As[row * LDK + kp] =
          *(const uint4*)&A[(size_t)(m0 + row) * K + k0 + kp];
    }
#pragma unroll
    for (int idx = tid; idx < BN * 4; idx += 256) {
      const int row = idx >> 2, kp = (idx & 3) * 8;
      *(uint4*)&Bs[row * LDK + kp] =
          *(const uint4*)&Bt[(size_t)(n0 + row) * K + k0 + kp];
    }
    __syncthreads();
    short8 af[TM], bf[TN];
#pragma unroll
    for (int i = 0; i < TM; i++)
      af[i] = *(const short8*)&As[(wrow + i * 16 + l15) * LDK + quad * 8];
#pragma unroll
    for (int j = 0; j < TN; j++)
      bf[j] = *(const short8*)&Bs[(wcol + j * 16 + l15) * LDK + quad * 8];
#pragma unroll
    for (int i = 0; i < TM; i++)
#pragma unroll
      for (int j = 0; j < TN; j++)
        acc[i][j] = __builtin_amdgcn_mfma_f32_16x16x32_bf16(af[i], bf[j],
                                                            acc[i][j], 0, 0, 0);
    __syncthreads();
  }

#pragma unroll
  for (int j = 0; j < TN; j++) {
    const int col = n0 + wcol + j * 16 + l15;
    const float bv = bias[col];
#pragma unroll
    for (int i = 0; i < TM; i++) {
#pragma unroll
      for (int r = 0; r < 4; r++) {
        const int row = m0 + wrow + i * 16 + quad * 4 + r;
        const float v = acc[i][j][r] + bv;
        if (OUT_BF16)
          ((ushort*)Cout)[(size_t)row * N + col] = f2bf(v);
        else
          ((float*)Cout)[(size_t)row * N + col] = v;
      }
    }
  }
}

// ---------------------------------------------------------------------------
// V transpose: qkvb[b*S + j][2048 + h*64 + d] -> vt[bh][d][j]   (bf16)
// ---------------------------------------------------------------------------
__global__ __launch_bounds__(256) void vtrans(const ushort* __restrict__ qkvb,
                                              ushort* __restrict__ vt) {
  __shared__ ushort T[64 * 72];
  const int j0 = blockIdx.x * 64, bh = blockIdx.y;
  const int b = bh >> 4, h = bh & 15;
  const int t = threadIdx.x;
#pragma unroll
  for (int u = 0; u < 2; u++) {
    const int idx = t + 256 * u;
    const int row = idx >> 3, p = idx & 7;
    *(uint4*)&T[row * 72 + p * 8] = *(const uint4*)&qkvb[
        (size_t)((b << 10) + j0 + row) * 3072 + 2048 + h * 64 + p * 8];
  }
  __syncthreads();
#pragma unroll
  for (int u = 0; u < 2; u++) {
    const int idx = t + 256 * u;
    const int d = idx >> 3, p = idx & 7;
    ushort tmp[8];
#pragma unroll
    for (int kk = 0; kk < 8; kk++) tmp[kk] = T[(p * 8 + kk) * 72 + d];
    uint4 o;
    __builtin_memcpy(&o, tmp, 16);
    *(uint4*)&vt[((size_t)bh * 64 + d) * 1024 + j0 + p * 8] = o;
  }
}

// ---------------------------------------------------------------------------
// MFMA attention with LDS-explicit softmax reductions.
// grid (S/16, B*H), block 256 = 4 waves.
// ---------------------------------------------------------------------------
__global__ __launch_bounds__(256) void attn_mfma(
    const ushort* __restrict__ qkvb,  // [4096][3072] bf16
    const ushort* __restrict__ vt,    // [64][64][1024] bf16
    const float* __restrict__ mask,   // [4][1024]
    float* __restrict__ w_out,        // [64][1024][1024]
    ushort* __restrict__ ab) {        // [4096][1024] bf16 merged heads
  constexpr int LDP = 1032;
  __shared__ ushort Ps[16 * LDP];   // probs bf16, 33 KB
  __shared__ float PM[16][68];      // per-row partial maxes
  __shared__ float PSum[16][68];    // per-row partial sums

  const int qt = blockIdx.x, bh = blockIdx.y;
  const int b = bh >> 4, h = bh & 15;
  const int q0 = qt * 16;
  const int tid = threadIdx.x;
  const int wv = tid >> 6, lane = tid & 63;
  const int l15 = lane & 15, quad = lane >> 4;
  const int slot = wv * 16 + l15;

  // Q fragments (A operand: m = l15, k = quad*8+j)
  const size_t rowQ = (size_t)((b << 10) + q0 + l15) * 3072 + h * 64;
  const short8 qf0 = *(const short8*)&qkvb[rowQ + quad * 8];
  const short8 qf1 = *(const short8*)&qkvb[rowQ + 32 + quad * 8];

  float sreg[16][4];

  // ---- scores ----
#pragma unroll
  for (int i = 0; i < 16; i++) {
    const int j0 = (wv + 4 * i) * 16;
    const int col = j0 + l15;
    const float mv = mask[(b << 10) + col];
    if (j0 <= q0 + 15) {
      const size_t rowK = (size_t)((b << 10) + j0 + l15) * 3072 + 1024 + h * 64;
      const short8 kf0 = *(const short8*)&qkvb[rowK + quad * 8];
      const short8 kf1 = *(const short8*)&qkvb[rowK + 32 + quad * 8];
      f32x4 c = {0.f, 0.f, 0.f, 0.f};
      c = __builtin_amdgcn_mfma_f32_16x16x32_bf16(qf0, kf0, c, 0, 0, 0);
      c = __builtin_amdgcn_mfma_f32_16x16x32_bf16(qf1, kf1, c, 0, 0, 0);
#pragma unroll
      for (int r = 0; r < 4; r++)
        sreg[i][r] =
            (col <= q0 + quad * 4 + r ? c[r] * 0.125f : -10000.0f) + mv;
    } else {
#pragma unroll
      for (int r = 0; r < 4; r++) sreg[i][r] = -10000.0f + mv;
    }
  }

  // ---- per-lane partial max per row -> PM[row][slot] ----
#pragma unroll
  for (int r = 0; r < 4; r++) {
    float m = sreg[0][r];
#pragma unroll
    for (int i = 1; i < 16; i++) m = fmaxf(m, sreg[i][r]);
    PM[quad * 4 + r][slot] = m;
  }
  __syncthreads();

  // ---- row max, exp (clamped), partial sums ----
  float mrow[4], psum[4];
#pragma unroll
  for (int r = 0; r < 4; r++) {
    float m = PM[quad * 4 + r][0];
    for (int t = 1; t < 64; t++) m = fmaxf(m, PM[quad * 4 + r][t]);
    mrow[r] = m;
    psum[r] = 0.f;
  }
#pragma unroll
  for (int i = 0; i < 16; i++)
#pragma unroll
    for (int r = 0; r < 4; r++) {
      const float e = __expf(fminf(sreg[i][r] - mrow[r], 0.0f));
      sreg[i][r] = e;
      psum[r] += e;
    }
#pragma unroll
  for (int r = 0; r < 4; r++) PSum[quad * 4 + r][slot] = psum[r];
  __syncthreads();

  float inv4[4];
#pragma unroll
  for (int r = 0; r < 4; r++) {
    float s = 0.f;
    for (int t = 0; t < 64; t++) s += PSum[quad * 4 + r][t];
    inv4[r] = 1.0f / fmaxf(s, 1e-30f);
  }

  // ---- write w (fp32) + stash probs bf16 into LDS ----
#pragma unroll
  for (int i = 0; i < 16; i++) {
    const int j0 = (wv + 4 * i) * 16;
#pragma unroll
    for (int r = 0; r < 4; r++) {
      const float p = sreg[i][r] * inv4[r];
      w_out[((size_t)(bh << 10) + q0 + quad * 4 + r) * 1024 + j0 + l15] = p;
      Ps[(quad * 4 + r) * LDP + j0 + l15] = f2bf(p);
    }
  }
  __syncthreads();

  // ---- PV: A = Ps (A-frag m=l15, k=quad*8+j), B = Vt[bh][d][key] ----
  f32x4 oacc = {0.f, 0.f, 0.f, 0.f};
  const int nch = (q0 + 16 + 31) >> 5;
  const ushort* vbase = vt + ((size_t)bh * 64 + wv * 16 + l15) * 1024;
  for (int c = 0; c < nch; c++) {
    const int k0 = c * 32;
    const short8 pf = *(const short8*)&Ps[l15 * LDP + k0 + quad * 8];
    const short8 vf = *(const short8*)&vbase[k0 + quad * 8];
    oacc = __builtin_amdgcn_mfma_f32_16x16x32_bf16(pf, vf, oacc, 0, 0, 0);
  }
#pragma unroll
  for (int r = 0; r < 4; r++) {
    ab[(size_t)((b << 10) + q0 + quad * 4 + r) * 1024 + h * 64 + wv * 16 +
       l15] = f2bf(oacc[r]);
  }
}

// ---------------------------------------------------------------------------
extern "C" void kernel_launch(void* const* d_in, const int* in_sizes, int n_in,
                              void* d_out, int out_size, void* d_ws,
                              size_t ws_size, hipStream_t stream) {
  const float* x = (const float*)d_in[0];
  const float* mask = (const float*)d_in[1];
  const float* w_attn = (const float*)d_in[2];
  const float* b_attn = (const float*)d_in[3];
  const float* w_proj = (const float*)d_in[4];
  const float* b_proj = (const float*)d_in[5];

  float* out_a = (float*)d_out;                 // [4,1024,1024]
  float* out_w = out_a + (size_t)Bb * Ss * Dd;  // [4,16,1024,1024]

  char* ws = (char*)d_ws;
  ushort* xb   = (ushort*)(ws);                  //  8 MB
  ushort* wta  = (ushort*)(ws + (8u << 20));     //  6 MB
  ushort* wtp  = (ushort*)(ws + (14u << 20));    //  2 MB
  ushort* qkvb = (ushort*)(ws + (16u << 20));    // 24 MB
  ushort* vt   = (ushort*)(ws + (40u << 20));    //  8 MB
  ushort* ab   = (ushort*)(ws + (48u << 20));    //  8 MB

  cast_f32_bf16<<<(Bb * Ss * Dd) / 1024, 256, 0, stream>>>(x, xb);
  transpose_cast<<<dim3(3 * Dd / 32, Dd / 32), 256, 0, stream>>>(w_attn, wta,
                                                                 Dd, 3 * Dd);
  transpose_cast<<<dim3(Dd / 32, Dd / 32), 256, 0, stream>>>(w_proj, wtp, Dd,
                                                             Dd);
  gemm_bt<128, 128, true><<<dim3(3 * Dd / 128, Bb * Ss / 128), 256, 0,
                            stream>>>(xb, wta, b_attn, qkvb, Bb * Ss, 3 * Dd,
                                      Dd);
  vtrans<<<dim3(Ss / 64, Bb * Hh), 256, 0, stream>>>(qkvb, vt);
  attn_mfma<<<dim3(Ss / 16, Bb * Hh), 256, 0, stream>>>(qkvb, vt, mask, out_w,
                                                        ab);
  gemm_bt<128, 64, false><<<dim3(Dd / 64, Bb * Ss / 128), 256, 0, stream>>>(
      ab, wtp, b_proj, out_a, Bb * Ss, Dd, Dd);
}